// Round 5
// baseline (118.112 us; speedup 1.0000x reference)
//
#include <hip/hip_runtime.h>

// Bicubic (Catmull-Rom) warped interpolation, LDS-tiled with dual-phase bf16.
// img/delta_x/delta_y: [B,C,H,W] fp32; out: [B,C,H,W] fp32 clipped to [0,1].
// H = W = 1024. 64x64 output tile / 256-thread block; 80x80 patch staged in
// LDS as bf16 in TWO phase-shifted copies:
//   copy0 dword j = elements (2j, 2j+1);  copy1 dword j = (2j+1, 2j+2)
// so any 4-tap window lx..lx+3 is 2 adjacent dwords of copy (lx&1) at pair
// p = lx>>1 -> one ds_read2_b32 per tap row (4 LDS instrs/pixel vs 16 b32).
// Out-of-patch taps (|delta| > ~6) take a rare fp32 global fallback.

#define HD 1024
#define WD 1024
#define TILE 64
#define HALO 8
#define SROWS 80          // staged rows
#define NPAIR 40          // bf16 pairs (dwords) of valid data per row
#define PSTR 41           // dword stride per row (odd; 41 % 32 == 9)
#define COFF 3296         // copy1 offset in dwords (80*41=3280, padded to %32==0)

__device__ __forceinline__ uint32_t bf16rtn(float f) {
    uint32_t u = __float_as_uint(f);
    u += 0x7fffu + ((u >> 16) & 1u);   // round-to-nearest-even
    return u >> 16;
}
__device__ __forceinline__ uint32_t packbf(float a, float b) {
    return bf16rtn(a) | (bf16rtn(b) << 16);
}
__device__ __forceinline__ float bflo(uint32_t u) { return __uint_as_float(u << 16); }
__device__ __forceinline__ float bfhi(uint32_t u) { return __uint_as_float(u & 0xffff0000u); }

__device__ __forceinline__ float cubic_gather_global(
    const float* __restrict__ p, int x0, int y0,
    float wxm1, float wx0, float wx1, float wx2,
    float wym1, float wy0, float wy1, float wy2)
{
    int cx0 = min(max(x0 - 1, 0), WD - 1);
    int cx1 = min(max(x0,     0), WD - 1);
    int cx2 = min(max(x0 + 1, 0), WD - 1);
    int cx3 = min(max(x0 + 2, 0), WD - 1);
    int cy0 = min(max(y0 - 1, 0), HD - 1);
    int cy1 = min(max(y0,     0), HD - 1);
    int cy2 = min(max(y0 + 1, 0), HD - 1);
    int cy3 = min(max(y0 + 2, 0), HD - 1);
    const float* r0 = p + (size_t)cy0 * WD;
    const float* r1 = p + (size_t)cy1 * WD;
    const float* r2 = p + (size_t)cy2 * WD;
    const float* r3 = p + (size_t)cy3 * WD;
    float s0 = wxm1 * r0[cx0] + wx0 * r0[cx1] + wx1 * r0[cx2] + wx2 * r0[cx3];
    float s1 = wxm1 * r1[cx0] + wx0 * r1[cx1] + wx1 * r1[cx2] + wx2 * r1[cx3];
    float s2 = wxm1 * r2[cx0] + wx0 * r2[cx1] + wx1 * r2[cx2] + wx2 * r2[cx3];
    float s3 = wxm1 * r3[cx0] + wx0 * r3[cx1] + wx1 * r3[cx2] + wx2 * r3[cx3];
    return wym1 * s0 + wy0 * s1 + wy1 * s2 + wy2 * s3;
}

__global__ __launch_bounds__(256) void bicubic_tile_kernel(
    const float* __restrict__ img,
    const float* __restrict__ dxp,
    const float* __restrict__ dyp,
    float* __restrict__ out)
{
    __shared__ uint32_t smp[2 * COFF];

    const int bx = blockIdx.x * TILE;
    const int by = blockIdx.y * TILE;
    const int plane = blockIdx.z;
    const float* __restrict__ p = img + (size_t)plane * (size_t)(HD * WD);

    const int gx0 = bx - HALO;
    const int gy0 = by - HALO;
    const int tid = threadIdx.x;

    // ---- stage 80 rows x 40 bf16-pairs (x2 copies), edge-clamped ----
    if (gx0 >= 0 && gx0 + 4 * (NPAIR / 2) * 2 < WD) {   // gx0+80 <= 1023
        // interior in x: float4 + 1 scalar load per quad of 4 elements
        for (int s = tid; s < SROWS * (NPAIR / 2); s += 256) {
            int r = s / (NPAIR / 2);
            int q = s - r * (NPAIR / 2);
            int gy = min(max(gy0 + r, 0), HD - 1);
            const float* rowp = p + (size_t)gy * WD + gx0;
            float4 v = *reinterpret_cast<const float4*>(rowp + 4 * q);
            float v4 = rowp[4 * q + 4];
            int b = r * PSTR + 2 * q;
            smp[b]            = packbf(v.x, v.y);   // copy0: (4q,   4q+1)
            smp[b + 1]        = packbf(v.z, v.w);   // copy0: (4q+2, 4q+3)
            smp[COFF + b]     = packbf(v.y, v.z);   // copy1: (4q+1, 4q+2)
            smp[COFF + b + 1] = packbf(v.w, v4);    // copy1: (4q+3, 4q+4)
        }
    } else {
        // x-edge tile: per-pair scalar staging with clamp
        for (int s = tid; s < SROWS * NPAIR; s += 256) {
            int r = s / NPAIR;
            int j = s - r * NPAIR;
            int gy = min(max(gy0 + r, 0), HD - 1);
            const float* rowp = p + (size_t)gy * WD;
            int e0 = min(max(gx0 + 2 * j,     0), WD - 1);
            int e1 = min(max(gx0 + 2 * j + 1, 0), WD - 1);
            int e2 = min(max(gx0 + 2 * j + 2, 0), WD - 1);
            float v0 = rowp[e0], v1 = rowp[e1], v2 = rowp[e2];
            int b = r * PSTR + j;
            smp[b]        = packbf(v0, v1);
            smp[COFF + b] = packbf(v1, v2);
        }
    }
    __syncthreads();

    // ---- compute: lane = column (64 consecutive cols/wave), 16 rows/thread
    const int col = bx + (tid & 63);
    const int rbase = by + (tid >> 6);

    // x_map = ((x + dx - 512)/511 + 1)*511.5 == (x-512)*s + 511.5 + dx*s
    const float s = 511.5f / 511.0f;
    const float colA = ((float)col - 512.0f) * s + 511.5f;

    #pragma unroll 4
    for (int it = 0; it < 16; ++it) {
        const int y = rbase + it * 4;
        const int didx = (plane << 20) | (y << 10) | col;

        const float ddx = dxp[didx];
        const float ddy = dyp[didx];

        const float yA = ((float)y - 512.0f) * s + 511.5f;
        float x_map = fmaf(ddx, s, colA);
        float y_map = fmaf(ddy, s, yA);

        float x0f = floorf(x_map);
        float y0f = floorf(y_map);
        float tx = x_map - x0f;
        float ty = y_map - y0f;
        int x0 = (int)x0f;
        int y0 = (int)y0f;

        float tx2 = tx * tx, tx3 = tx2 * tx;
        float wxm1 = (-tx3 + 2.0f * tx2 - tx) * 0.5f;
        float wx0  = (3.0f * tx3 - 5.0f * tx2 + 2.0f) * 0.5f;
        float wx1  = (-3.0f * tx3 + 4.0f * tx2 + tx) * 0.5f;
        float wx2  = 1.0f - (wxm1 + wx0 + wx1);

        float ty2 = ty * ty, ty3 = ty2 * ty;
        float wym1 = (-ty3 + 2.0f * ty2 - ty) * 0.5f;
        float wy0  = (3.0f * ty3 - 5.0f * ty2 + 2.0f) * 0.5f;
        float wy1  = (-3.0f * ty3 + 4.0f * ty2 + ty) * 0.5f;
        float wy2  = 1.0f - (wym1 + wy0 + wy1);

        const int lx = x0 - 1 - gx0;
        const int ly = y0 - 1 - gy0;
        const bool inb = (lx >= 0) & (lx <= SROWS - 4) & (ly >= 0) & (ly <= SROWS - 4);

        float acc;
        if (inb) {
            const uint32_t* bp = smp + ((lx & 1) ? COFF : 0) + ly * PSTR + (lx >> 1);
            uint32_t a0 = bp[0],            a1 = bp[1];             // row 0
            uint32_t b0 = bp[PSTR],         b1 = bp[PSTR + 1];      // row 1
            uint32_t c0 = bp[2 * PSTR],     c1 = bp[2 * PSTR + 1];  // row 2
            uint32_t d0 = bp[3 * PSTR],     d1 = bp[3 * PSTR + 1];  // row 3
            float s0 = wxm1 * bflo(a0) + wx0 * bfhi(a0) + wx1 * bflo(a1) + wx2 * bfhi(a1);
            float s1 = wxm1 * bflo(b0) + wx0 * bfhi(b0) + wx1 * bflo(b1) + wx2 * bfhi(b1);
            float s2 = wxm1 * bflo(c0) + wx0 * bfhi(c0) + wx1 * bflo(c1) + wx2 * bfhi(c1);
            float s3 = wxm1 * bflo(d0) + wx0 * bfhi(d0) + wx1 * bflo(d1) + wx2 * bfhi(d1);
            acc = wym1 * s0 + wy0 * s1 + wy1 * s2 + wy2 * s3;
        } else {
            acc = cubic_gather_global(p, x0, y0, wxm1, wx0, wx1, wx2,
                                      wym1, wy0, wy1, wy2);
        }
        out[didx] = fminf(fmaxf(acc, 0.0f), 1.0f);
    }
}

extern "C" void kernel_launch(void* const* d_in, const int* in_sizes, int n_in,
                              void* d_out, int out_size, void* d_ws, size_t ws_size,
                              hipStream_t stream) {
    const float* img = (const float*)d_in[0];
    const float* dxp = (const float*)d_in[1];
    const float* dyp = (const float*)d_in[2];
    float* out = (float*)d_out;

    const int planes = in_sizes[0] / (HD * WD);  // B*C = 24
    dim3 grid(WD / TILE, HD / TILE, planes);
    bicubic_tile_kernel<<<grid, 256, 0, stream>>>(img, dxp, dyp, out);
}

// Round 6
// 94.716 us; speedup vs baseline: 1.2470x; 1.2470x over previous
//
#include <hip/hip_runtime.h>

// Bicubic (Catmull-Rom) warped interpolation, LDS-tiled + register-prefetched
// deltas. img/delta_x/delta_y: [B,C,H,W] fp32; out: fp32 clipped to [0,1].
// H = W = 1024. 64x64 output tile / 256-thread block; 80x80 fp32 patch staged
// in LDS (stride 83 -> 26.6KB -> 6 blocks/CU). Lane = column (stride-1).
// All 16 iterations' dx/dy loads are hoisted into registers right after the
// staging barrier so HBM latency (~900cy) is hidden under compute.
// Out-of-patch taps (|delta| > ~6) take a rare fp32 global fallback.

#define HD 1024
#define WD 1024
#define TILE 64
#define HALO 8
#define SROWS 80   // staged rows & cols of valid data
#define SSTR 83    // LDS row stride in floats (83*4B; 80x83x4 = 26.56KB)

__device__ __forceinline__ float cubic_gather_global(
    const float* __restrict__ p, int x0, int y0,
    float wxm1, float wx0, float wx1, float wx2,
    float wym1, float wy0, float wy1, float wy2)
{
    int cx0 = min(max(x0 - 1, 0), WD - 1);
    int cx1 = min(max(x0,     0), WD - 1);
    int cx2 = min(max(x0 + 1, 0), WD - 1);
    int cx3 = min(max(x0 + 2, 0), WD - 1);
    int cy0 = min(max(y0 - 1, 0), HD - 1);
    int cy1 = min(max(y0,     0), HD - 1);
    int cy2 = min(max(y0 + 1, 0), HD - 1);
    int cy3 = min(max(y0 + 2, 0), HD - 1);
    const float* r0 = p + (size_t)cy0 * WD;
    const float* r1 = p + (size_t)cy1 * WD;
    const float* r2 = p + (size_t)cy2 * WD;
    const float* r3 = p + (size_t)cy3 * WD;
    float s0 = wxm1 * r0[cx0] + wx0 * r0[cx1] + wx1 * r0[cx2] + wx2 * r0[cx3];
    float s1 = wxm1 * r1[cx0] + wx0 * r1[cx1] + wx1 * r1[cx2] + wx2 * r1[cx3];
    float s2 = wxm1 * r2[cx0] + wx0 * r2[cx1] + wx1 * r2[cx2] + wx2 * r2[cx3];
    float s3 = wxm1 * r3[cx0] + wx0 * r3[cx1] + wx1 * r3[cx2] + wx2 * r3[cx3];
    return wym1 * s0 + wy0 * s1 + wy1 * s2 + wy2 * s3;
}

__global__ __launch_bounds__(256) void bicubic_tile_kernel(
    const float* __restrict__ img,
    const float* __restrict__ dxp,
    const float* __restrict__ dyp,
    float* __restrict__ out)
{
    __shared__ float sm[SROWS * SSTR];

    const int bx = blockIdx.x * TILE;
    const int by = blockIdx.y * TILE;
    const int plane = blockIdx.z;
    const float* __restrict__ p = img + (size_t)plane * (size_t)(HD * WD);

    const int gx0 = bx - HALO;
    const int gy0 = by - HALO;
    const int tid = threadIdx.x;

    // ---- stage 80x80 patch at (gy0, gx0) into LDS (edge-clamped) ----
    if (gx0 >= 0 && gx0 + SROWS <= WD) {
        for (int s = tid; s < SROWS * (SROWS / 4); s += 256) {
            int r = s / (SROWS / 4);
            int q = s - r * (SROWS / 4);
            int gy = min(max(gy0 + r, 0), HD - 1);
            float4 v = *reinterpret_cast<const float4*>(p + (size_t)gy * WD + gx0 + 4 * q);
            int b = r * SSTR + 4 * q;
            sm[b + 0] = v.x; sm[b + 1] = v.y; sm[b + 2] = v.z; sm[b + 3] = v.w;
        }
    } else {
        for (int s = tid; s < SROWS * SROWS; s += 256) {
            int r = s / SROWS;
            int c = s - r * SROWS;
            int gy = min(max(gy0 + r, 0), HD - 1);
            int gx = min(max(gx0 + c, 0), WD - 1);
            sm[r * SSTR + c] = p[(size_t)gy * WD + gx];
        }
    }
    __syncthreads();

    // ---- compute: lane = column (64 consecutive cols/wave), 16 rows/thread
    const int col = bx + (tid & 63);
    const int rbase = by + (tid >> 6);
    const int didx0 = (plane << 20) | (rbase << 10) | col;

    // hoist ALL delta loads: issued back-to-back, consumed progressively ->
    // vmcnt tracking pipelines them and HBM latency hides under compute
    float vdx[16], vdy[16];
    #pragma unroll
    for (int it = 0; it < 16; ++it) {
        vdx[it] = dxp[didx0 + it * 4096];
        vdy[it] = dyp[didx0 + it * 4096];
    }

    // x_map = ((x + dx - 512)/511 + 1)*511.5 == (x-512)*s + 511.5 + dx*s
    const float s = 511.5f / 511.0f;
    const float colA = ((float)col - 512.0f) * s + 511.5f;
    const float yA0 = ((float)rbase - 512.0f) * s + 511.5f;
    const float yStep = 4.0f * s;

    #pragma unroll
    for (int it = 0; it < 16; ++it) {
        const int didx = didx0 + it * 4096;
        const float ddx = vdx[it];
        const float ddy = vdy[it];

        float x_map = fmaf(ddx, s, colA);
        float y_map = fmaf(ddy, s, yA0 + (float)it * yStep);

        float x0f = floorf(x_map);
        float y0f = floorf(y_map);
        float tx = x_map - x0f;
        float ty = y_map - y0f;
        int x0 = (int)x0f;
        int y0 = (int)y0f;

        float tx2 = tx * tx, tx3 = tx2 * tx;
        float wxm1 = (-tx3 + 2.0f * tx2 - tx) * 0.5f;
        float wx0  = (3.0f * tx3 - 5.0f * tx2 + 2.0f) * 0.5f;
        float wx1  = (-3.0f * tx3 + 4.0f * tx2 + tx) * 0.5f;
        float wx2  = 1.0f - (wxm1 + wx0 + wx1);

        float ty2 = ty * ty, ty3 = ty2 * ty;
        float wym1 = (-ty3 + 2.0f * ty2 - ty) * 0.5f;
        float wy0  = (3.0f * ty3 - 5.0f * ty2 + 2.0f) * 0.5f;
        float wy1  = (-3.0f * ty3 + 4.0f * ty2 + ty) * 0.5f;
        float wy2  = 1.0f - (wym1 + wy0 + wy1);

        // raw tap window (LDS holds edge-clamped values; no per-tap clamps)
        const int lx = x0 - 1 - gx0;
        const int ly = y0 - 1 - gy0;
        const bool inb = (lx >= 0) & (lx <= SROWS - 4) & (ly >= 0) & (ly <= SROWS - 4);

        float acc;
        if (inb) {
            const float* b = &sm[ly * SSTR + lx];
            float s0 = wxm1 * b[0 * SSTR + 0] + wx0 * b[0 * SSTR + 1] + wx1 * b[0 * SSTR + 2] + wx2 * b[0 * SSTR + 3];
            float s1 = wxm1 * b[1 * SSTR + 0] + wx0 * b[1 * SSTR + 1] + wx1 * b[1 * SSTR + 2] + wx2 * b[1 * SSTR + 3];
            float s2 = wxm1 * b[2 * SSTR + 0] + wx0 * b[2 * SSTR + 1] + wx1 * b[2 * SSTR + 2] + wx2 * b[2 * SSTR + 3];
            float s3 = wxm1 * b[3 * SSTR + 0] + wx0 * b[3 * SSTR + 1] + wx1 * b[3 * SSTR + 2] + wx2 * b[3 * SSTR + 3];
            acc = wym1 * s0 + wy0 * s1 + wy1 * s2 + wy2 * s3;
        } else {
            acc = cubic_gather_global(p, x0, y0, wxm1, wx0, wx1, wx2,
                                      wym1, wy0, wy1, wy2);
        }
        out[didx] = fminf(fmaxf(acc, 0.0f), 1.0f);
    }
}

extern "C" void kernel_launch(void* const* d_in, const int* in_sizes, int n_in,
                              void* d_out, int out_size, void* d_ws, size_t ws_size,
                              hipStream_t stream) {
    const float* img = (const float*)d_in[0];
    const float* dxp = (const float*)d_in[1];
    const float* dyp = (const float*)d_in[2];
    float* out = (float*)d_out;

    const int planes = in_sizes[0] / (HD * WD);  // B*C = 24
    dim3 grid(WD / TILE, HD / TILE, planes);
    bicubic_tile_kernel<<<grid, 256, 0, stream>>>(img, dxp, dyp, out);
}